// Round 7
// baseline (20.095 us; speedup 1.0000x reference)
//
#include <hip/hip_runtime.h>

typedef _Float16 half2_t __attribute__((ext_vector_type(2)));
typedef __fp16   fp16x2_t __attribute__((ext_vector_type(2)));

constexpr int M_NODES = 4096;
constexpr int T_IN    = 24;
constexpr int HIDN    = 64;
constexpr int HOR     = 10;
constexpr int NB      = 64;    // blocks; each owns 64 output nodes, ODE is redundant

constexpr float TWO_LOG2E = 2.8853900817779268f;   // 2*log2(e)

__device__ __forceinline__ float fdot2f16(half2_t a, half2_t b, float c) {
#if __has_builtin(__builtin_amdgcn_fdot2)
    return __builtin_amdgcn_fdot2(a, b, c, false);
#else
    return fmaf((float)a[0], (float)b[0], fmaf((float)a[1], (float)b[1], c));
#endif
}

template<int CTRL>
__device__ __forceinline__ float dpp_add(float v) {
    int t = __builtin_amdgcn_update_dpp(0, __float_as_int(v), CTRL, 0xf, 0xf, true);
    return v + __int_as_float(t);
}

// 64-lane sum, uniform result: 4-step DPP butterfly (row sums) + 4 const readlanes.
__device__ __forceinline__ float wave_allsum(float v) {
    v = dpp_add<0xB1>(v);    // quad_perm(1,0,3,2)  = xor1
    v = dpp_add<0x4E>(v);    // quad_perm(2,3,0,1)  = xor2
    v = dpp_add<0x141>(v);   // row_half_mirror     = xor4
    v = dpp_add<0x140>(v);   // row_mirror          = xor8 -> all lanes hold row sum
    float s0 = __int_as_float(__builtin_amdgcn_readlane(__float_as_int(v), 0));
    float s1 = __int_as_float(__builtin_amdgcn_readlane(__float_as_int(v), 16));
    float s2 = __int_as_float(__builtin_amdgcn_readlane(__float_as_int(v), 32));
    float s3 = __int_as_float(__builtin_amdgcn_readlane(__float_as_int(v), 48));
    return (s0 + s1) + (s2 + s3);
}

__global__ __launch_bounds__(256, 1) void fused_gode_kernel(
    const float* __restrict__ x,
    const float* __restrict__ W1, const float* __restrict__ b1,
    const float* __restrict__ W2, const float* __restrict__ b2,
    const float* __restrict__ W3, const float* __restrict__ b3,
    float* __restrict__ out)
{
    const int tid  = threadIdx.x;
    const int lane = tid & 63;
    const int wid  = tid >> 6;

    __shared__ float psum[256];
    __shared__ float cs[HOR];
    __shared__ float ys[64 + 1];            // this block's y0 slice

    const int nbase = blockIdx.x * (M_NODES / NB);   // 64 nodes per block

    // wave 0: issue weight loads FIRST (latency hides under the reduction)
    float w2f[HIDN];
    float ew1 = 0.f, eb1 = 0.f, cb2 = 0.f, w3 = 0.f, bb3 = 0.f;
    if (wid == 0) {
        #pragma unroll
        for (int i = 0; i < HIDN; ++i) w2f[i] = W2[i * HIDN + lane];  // column `lane`
        ew1 = W1[lane] * TWO_LOG2E;       // folded: exp2(y*ew1 + eb1) = exp(2*(y*w1+b1))
        eb1 = b1[lane] * TWO_LOG2E;
        cb2 = b2[lane] * TWO_LOG2E;
        w3  = W3[lane];
        bb3 = b3[0];
    }
    // wave 1: load this block's y0 slice for the write phase
    if (wid == 1) ys[lane] = x[(nbase + lane) * T_IN + (T_IN - 1)];

    // ---- redundant full reduction (identical FP order in every block) ----
    float s = 0.f;
    #pragma unroll
    for (int k = 0; k < M_NODES / 256; ++k)
        s += x[(tid + 256 * k) * T_IN + (T_IN - 1)];
    psum[tid] = s;
    __syncthreads();

    // ---- wave 0: serial scalar ODE (redundant per block, bitwise identical) ----
    if (wid == 0) {
        float t4 = psum[lane] + psum[lane + 64] + psum[lane + 128] + psum[lane + 192];
        float mu = wave_allsum(t4) * (1.0f / (float)M_NODES);

        half2_t w2h[HIDN / 2];                       // (W2[2a][lane], W2[2a+1][lane])
        #pragma unroll
        for (int i = 0; i < HIDN; i += 2)
            w2h[i / 2] = half2_t{(_Float16)w2f[i], (_Float16)w2f[i + 1]};

        // f(y): layer1 per-lane tanh; layer2 via readlane+dot2 (no LDS, no barriers);
        // layer3 via DPP allsum. All register-resident.
        auto feval = [&](float y) -> float {
            // h1[lane] = tanh(y*w1+b1) = 1 - 2/(exp2(y*ew1+eb1)+1)
            float h1 = 1.f - 2.f * __builtin_amdgcn_rcpf(
                           __builtin_amdgcn_exp2f(fmaf(y, ew1, eb1)) + 1.f);
            // pack (h1[2a], h1[2a+1]) at even lanes via DPP xor1 partner
            int   hp = __builtin_amdgcn_update_dpp(0, __float_as_int(h1), 0xB1, 0xf, 0xf, true);
            fp16x2_t pk0 = __builtin_amdgcn_cvt_pkrtz(h1, __int_as_float(hp));
            int   pki = __builtin_bit_cast(int, pk0);
            float acc[8] = {0.f, 0.f, 0.f, 0.f, 0.f, 0.f, 0.f, 0.f};
            #pragma unroll
            for (int a = 0; a < 32; ++a) {           // static lane idx, static acc idx
                int sv = __builtin_amdgcn_readlane(pki, 2 * a);
                acc[a & 7] = fdot2f16(__builtin_bit_cast(half2_t, sv), w2h[a], acc[a & 7]);
            }
            float t = ((acc[0] + acc[1]) + (acc[2] + acc[3])) +
                      ((acc[4] + acc[5]) + (acc[6] + acc[7]));
            // h2[lane] = tanh(t + b2) = 1 - 2/(exp2(t*C + cb2)+1)
            float h2 = 1.f - 2.f * __builtin_amdgcn_rcpf(
                           __builtin_amdgcn_exp2f(fmaf(TWO_LOG2E, t, cb2)) + 1.f);
            return wave_allsum(h2 * w3) + bb3;
        };

        const float DT  = (float)HOR / (float)(HOR - 1);   // 10/9
        const float DT3 = DT * (1.f / 3.f);

        float c = 0.f;
        if (lane == 0) cs[0] = 0.f;
        for (int t = 1; t < HOR; ++t) {
            float k1 = feval(mu);
            float k2 = feval(fmaf(DT3, k1, mu));
            float k3 = feval(fmaf(DT, k2, fmaf(-DT3, k1, mu)));
            float k4 = feval(fmaf(DT, (k1 - k2) + k3, mu));
            float d  = DT * (k1 + 3.f * (k2 + k3) + k4) * 0.125f;
            mu += d;
            c  += d;
            if (lane == 0) cs[t] = c;
        }
    }
    __syncthreads();

    // ---- write this block's slice: 64 nodes x 10 = 640 floats = 160 float4 ----
    constexpr int NF4 = (M_NODES / NB) * HOR / 4;   // 160
    if (tid < NF4) {
        int e = tid * 4;
        int n = e / 10;
        int h = e - n * 10;
        float4 v;
        v.x = ys[n] + cs[h]; if (++h == 10) { h = 0; ++n; }
        v.y = ys[n] + cs[h]; if (++h == 10) { h = 0; ++n; }
        v.z = ys[n] + cs[h]; if (++h == 10) { h = 0; ++n; }
        v.w = ys[n] + cs[h];
        ((float4*)(out + nbase * HOR))[tid] = v;
    }
}

extern "C" void kernel_launch(void* const* d_in, const int* in_sizes, int n_in,
                              void* d_out, int out_size, void* d_ws, size_t ws_size,
                              hipStream_t stream) {
    const float* x  = (const float*)d_in[0];
    const float* W1 = (const float*)d_in[1];
    const float* b1 = (const float*)d_in[2];
    const float* W2 = (const float*)d_in[3];
    const float* b2 = (const float*)d_in[4];
    const float* W3 = (const float*)d_in[5];
    const float* b3 = (const float*)d_in[6];
    float* out = (float*)d_out;

    fused_gode_kernel<<<NB, 256, 0, stream>>>(x, W1, b1, W2, b2, W3, b3, out);
}

// Round 8
// 17.354 us; speedup vs baseline: 1.1579x; 1.1579x over previous
//
#include <hip/hip_runtime.h>

typedef _Float16 half2_t __attribute__((ext_vector_type(2)));
typedef _Float16 half8_t __attribute__((ext_vector_type(8)));

constexpr int M_NODES = 4096;
constexpr int T_IN    = 24;
constexpr int HIDN    = 64;
constexpr int HOR     = 10;
constexpr int NB      = 64;    // blocks; each owns 64 output nodes, ODE is redundant

constexpr float TWO_LOG2E = 2.8853900817779268f;   // 2*log2(e)

__device__ __forceinline__ float fdot2f16(half2_t a, half2_t b, float c) {
#if __has_builtin(__builtin_amdgcn_fdot2)
    return __builtin_amdgcn_fdot2(a, b, c, false);
#else
    return fmaf((float)a[0], (float)b[0], fmaf((float)a[1], (float)b[1], c));
#endif
}

// DPP full-wave (64-lane) sum -> uniform scalar via single readlane(63).
template<int CTRL, int ROW_MASK>
__device__ __forceinline__ float dpp_add(float v) {
    int t = __builtin_amdgcn_update_dpp(0, __float_as_int(v), CTRL, ROW_MASK, 0xf, true);
    return v + __int_as_float(t);
}
__device__ __forceinline__ float wave_allsum(float v) {
    v = dpp_add<0x111, 0xf>(v);   // row_shr:1
    v = dpp_add<0x112, 0xf>(v);   // row_shr:2
    v = dpp_add<0x114, 0xf>(v);   // row_shr:4
    v = dpp_add<0x118, 0xf>(v);   // row_shr:8
    v = dpp_add<0x142, 0xa>(v);   // row_bcast:15 -> rows 1,3
    v = dpp_add<0x143, 0xc>(v);   // row_bcast:31 -> rows 2,3; lane63 = total
    return __int_as_float(__builtin_amdgcn_readlane(__float_as_int(v), 63));
}

__global__ __launch_bounds__(256, 1) void fused_gode_kernel(
    const float* __restrict__ x,
    const float* __restrict__ W1, const float* __restrict__ b1,
    const float* __restrict__ W2, const float* __restrict__ b2,
    const float* __restrict__ W3, const float* __restrict__ b3,
    float* __restrict__ out)
{
    const int tid  = threadIdx.x;
    const int lane = tid & 63;
    const int wid  = tid >> 6;

    __shared__ float psum[256];
    __shared__ float cs[HOR];
    __shared__ __align__(16) _Float16 h1h[HIDN];
    __shared__ float ys[64 + 1];            // this block's y0 slice

    const int nbase = blockIdx.x * (M_NODES / NB);   // 64 nodes per block

    // wave 0: issue weight loads FIRST (latency hides under the reduction)
    float w2f[HIDN];
    float ew1 = 0.f, eb1 = 0.f, cb2 = 0.f, w3 = 0.f, bb3 = 0.f;
    if (wid == 0) {
        #pragma unroll
        for (int i = 0; i < HIDN; ++i) w2f[i] = W2[i * HIDN + lane];  // column `lane`
        ew1 = W1[lane] * TWO_LOG2E;       // exp2(y*ew1+eb1) = exp(2*(y*w1+b1))
        eb1 = b1[lane] * TWO_LOG2E;
        cb2 = b2[lane] * TWO_LOG2E;
        w3  = W3[lane];
        bb3 = b3[0];
    }
    // wave 1: load this block's y0 slice for the write phase
    if (wid == 1) ys[lane] = x[(nbase + lane) * T_IN + (T_IN - 1)];

    // ---- redundant full reduction (identical FP order in every block) ----
    float s = 0.f;
    #pragma unroll
    for (int k = 0; k < M_NODES / 256; ++k)
        s += x[(tid + 256 * k) * T_IN + (T_IN - 1)];
    psum[tid] = s;
    __syncthreads();

    // ---- wave 0: serial scalar ODE (redundant per block, bitwise identical) ----
    if (wid == 0) {
        float t4 = psum[lane] + psum[lane + 64] + psum[lane + 128] + psum[lane + 192];
        float mu = wave_allsum(t4) * (1.0f / (float)M_NODES);

        half2_t w2h[HIDN / 2];                       // (W2[2a][lane], W2[2a+1][lane])
        #pragma unroll
        for (int i = 0; i < HIDN; i += 2)
            w2h[i / 2] = half2_t{(_Float16)w2f[i], (_Float16)w2f[i + 1]};

        // feval on the folded-exponent argument earg = (y*w1+b1)*2log2e (per lane)
        auto feval = [&](float earg) -> float {
            // h1 = tanh(y*w1+b1) = 1 - 2/(exp2(earg)+1)
            float h1 = fmaf(-2.f, __builtin_amdgcn_rcpf(
                               __builtin_amdgcn_exp2f(earg) + 1.f), 1.f);
            h1h[lane] = (_Float16)h1;              // wave-synchronous LDS broadcast
            __builtin_amdgcn_wave_barrier();
            const half8_t* hv = (const half8_t*)h1h;
            float acc[8];
            #pragma unroll
            for (int r = 0; r < 8; ++r) {
                half8_t u = hv[r];                 // uniform addr -> broadcast
                half2_t p0{u[0], u[1]}, p1{u[2], u[3]}, p2{u[4], u[5]}, p3{u[6], u[7]};
                float a = fdot2f16(p0, w2h[4 * r + 0], 0.f);
                a = fdot2f16(p1, w2h[4 * r + 1], a);
                a = fdot2f16(p2, w2h[4 * r + 2], a);
                acc[r] = fdot2f16(p3, w2h[4 * r + 3], a);
            }
            float t = ((acc[0] + acc[1]) + (acc[2] + acc[3])) +
                      ((acc[4] + acc[5]) + (acc[6] + acc[7]));
            // h2 = tanh(t+b2) = 1 - 2/(exp2(t*2log2e + cb2)+1)
            float h2 = fmaf(-2.f, __builtin_amdgcn_rcpf(
                               __builtin_amdgcn_exp2f(fmaf(TWO_LOG2E, t, cb2)) + 1.f), 1.f);
            __builtin_amdgcn_wave_barrier();       // keep next h1h write after reads
            return wave_allsum(h2 * w3) + bb3;
        };

        const float DT   = (float)HOR / (float)(HOR - 1);   // 10/9
        const float DT3  = DT * (1.f / 3.f);
        const float dte  = DT * ew1;      // per-lane: DT*w1*2log2e
        const float dte3 = DT3 * ew1;

        float c = 0.f;
        if (lane == 0) cs[0] = 0.f;
        for (int t = 1; t < HOR; ++t) {
            float base = fmaf(mu, ew1, eb1);
            float k1 = feval(base);
            float k2 = feval(fmaf(k1, dte3, base));
            float k3 = feval(fmaf(k2, dte, fmaf(k1, -dte3, base)));
            float k4 = feval(fmaf((k1 - k2) + k3, dte, base));
            float d  = DT * (k1 + 3.f * (k2 + k3) + k4) * 0.125f;
            mu += d;
            c  += d;
            if (lane == 0) cs[t] = c;
        }
    }
    __syncthreads();

    // ---- write this block's slice: 64 nodes x 10 = 640 floats = 160 float4 ----
    constexpr int NF4 = (M_NODES / NB) * HOR / 4;   // 160
    if (tid < NF4) {
        int e = tid * 4;
        int n = e / 10;
        int h = e - n * 10;
        float4 v;
        v.x = ys[n] + cs[h]; if (++h == 10) { h = 0; ++n; }
        v.y = ys[n] + cs[h]; if (++h == 10) { h = 0; ++n; }
        v.z = ys[n] + cs[h]; if (++h == 10) { h = 0; ++n; }
        v.w = ys[n] + cs[h];
        ((float4*)(out + nbase * HOR))[tid] = v;
    }
}

extern "C" void kernel_launch(void* const* d_in, const int* in_sizes, int n_in,
                              void* d_out, int out_size, void* d_ws, size_t ws_size,
                              hipStream_t stream) {
    const float* x  = (const float*)d_in[0];
    const float* W1 = (const float*)d_in[1];
    const float* b1 = (const float*)d_in[2];
    const float* W2 = (const float*)d_in[3];
    const float* b2 = (const float*)d_in[4];
    const float* W3 = (const float*)d_in[5];
    const float* b3 = (const float*)d_in[6];
    float* out = (float*)d_out;

    fused_gode_kernel<<<NB, 256, 0, stream>>>(x, W1, b1, W2, b2, W3, b3, out);
}

// Round 9
// 16.979 us; speedup vs baseline: 1.1835x; 1.0221x over previous
//
#include <hip/hip_runtime.h>

typedef _Float16 half2_t __attribute__((ext_vector_type(2)));
typedef _Float16 half8_t __attribute__((ext_vector_type(8)));
typedef int      int2v   __attribute__((ext_vector_type(2)));

constexpr int M_NODES = 4096;
constexpr int T_IN    = 24;
constexpr int HIDN    = 64;
constexpr int HOR     = 10;
constexpr int NB      = 64;    // blocks; each owns 64 output nodes, ODE is redundant

constexpr float TWO_LOG2E = 2.8853900817779268f;   // 2*log2(e)

__device__ __forceinline__ float fdot2f16(half2_t a, half2_t b, float c) {
#if __has_builtin(__builtin_amdgcn_fdot2)
    return __builtin_amdgcn_fdot2(a, b, c, false);
#else
    return fmaf((float)a[0], (float)b[0], fmaf((float)a[1], (float)b[1], c));
#endif
}

template<int CTRL, int ROW_MASK>
__device__ __forceinline__ float dpp_add(float v) {
    int t = __builtin_amdgcn_update_dpp(0, __float_as_int(v), CTRL, ROW_MASK, 0xf, true);
    return v + __int_as_float(t);
}

// 64-lane all-reduce sum, result uniform in ALL lanes.
// 4 DPP steps (within 16-lane rows) + permlane16/32 swaps (gfx950) -> no
// readlane, no VALU->SGPR hazard. Fallback: row_bcast + readlane(63).
__device__ __forceinline__ float wave_allsum(float v) {
    v = dpp_add<0xB1,  0xf>(v);   // quad_perm(1,0,3,2) : xor1
    v = dpp_add<0x4E,  0xf>(v);   // quad_perm(2,3,0,1) : xor2
    v = dpp_add<0x141, 0xf>(v);   // row_half_mirror    : pairs quads
    v = dpp_add<0x140, 0xf>(v);   // row_mirror         : pairs 8-groups
#if __has_builtin(__builtin_amdgcn_permlane16_swap) && __has_builtin(__builtin_amdgcn_permlane32_swap)
    {   // {r[0],r[1]} = {v[l], v[l^16]} as a set -> sum is the butterfly step
        int2v r = __builtin_amdgcn_permlane16_swap(__float_as_int(v), __float_as_int(v), false, false);
        v = __int_as_float(r[0]) + __int_as_float(r[1]);
        int2v q = __builtin_amdgcn_permlane32_swap(__float_as_int(v), __float_as_int(v), false, false);
        v = __int_as_float(q[0]) + __int_as_float(q[1]);
    }
    return v;
#else
    v = dpp_add<0x142, 0xa>(v);   // row_bcast:15 -> rows 1,3
    v = dpp_add<0x143, 0xc>(v);   // row_bcast:31 -> rows 2,3; lane63 = total
    return __int_as_float(__builtin_amdgcn_readlane(__float_as_int(v), 63));
#endif
}

__global__ __launch_bounds__(256, 1) void fused_gode_kernel(
    const float* __restrict__ x,
    const float* __restrict__ W1, const float* __restrict__ b1,
    const float* __restrict__ W2, const float* __restrict__ b2,
    const float* __restrict__ W3, const float* __restrict__ b3,
    float* __restrict__ out)
{
    const int tid  = threadIdx.x;
    const int lane = tid & 63;
    const int wid  = tid >> 6;

    __shared__ float psum[256];
    __shared__ float cs[HOR];
    __shared__ __align__(16) _Float16 h1h[HIDN];
    __shared__ float ys[64 + 1];            // this block's y0 slice

    const int nbase = blockIdx.x * (M_NODES / NB);   // 64 nodes per block

    // wave 0: issue weight loads FIRST (latency hides under the reduction)
    float w2f[HIDN];
    float ew1 = 0.f, eb1 = 0.f, cb2 = 0.f, w3 = 0.f, w3m2 = 0.f, bb3 = 0.f;
    if (wid == 0) {
        #pragma unroll
        for (int i = 0; i < HIDN; ++i) w2f[i] = W2[i * HIDN + lane];  // column `lane`
        ew1  = W1[lane] * TWO_LOG2E;      // exp2(y*ew1+eb1) = exp(2*(y*w1+b1))
        eb1  = b1[lane] * TWO_LOG2E;
        cb2  = b2[lane] * TWO_LOG2E;
        w3   = W3[lane];
        w3m2 = -2.f * w3;
        bb3  = b3[0];
    }
    // wave 1: load this block's y0 slice for the write phase
    if (wid == 1) ys[lane] = x[(nbase + lane) * T_IN + (T_IN - 1)];

    // ---- redundant full reduction (identical FP order in every block) ----
    float s = 0.f;
    #pragma unroll
    for (int k = 0; k < M_NODES / 256; ++k)
        s += x[(tid + 256 * k) * T_IN + (T_IN - 1)];
    psum[tid] = s;
    __syncthreads();

    // ---- wave 0: serial scalar ODE (redundant per block, bitwise identical) ----
    if (wid == 0) {
        float t4 = psum[lane] + psum[lane + 64] + psum[lane + 128] + psum[lane + 192];
        float mu = wave_allsum(t4) * (1.0f / (float)M_NODES);

        half2_t w2h[HIDN / 2];                       // (W2[2a][lane], W2[2a+1][lane])
        #pragma unroll
        for (int i = 0; i < HIDN; i += 2)
            w2h[i / 2] = half2_t{(_Float16)w2f[i], (_Float16)w2f[i + 1]};

        // raw-sum feval: returns S where k = S + bb3 (bb3 folded off-path by caller)
        auto fevalS = [&](float earg) -> float {
            float h1 = fmaf(-2.f, __builtin_amdgcn_rcpf(
                               __builtin_amdgcn_exp2f(earg) + 1.f), 1.f);
            h1h[lane] = (_Float16)h1;              // wave-synchronous LDS broadcast
            __builtin_amdgcn_wave_barrier();
            const half8_t* hv = (const half8_t*)h1h;
            float acc[8];
            #pragma unroll
            for (int r = 0; r < 8; ++r) {
                half8_t u = hv[r];                 // uniform addr -> broadcast
                half2_t p0{u[0], u[1]}, p1{u[2], u[3]}, p2{u[4], u[5]}, p3{u[6], u[7]};
                float a = fdot2f16(p0, w2h[4 * r + 0], 0.f);
                a = fdot2f16(p1, w2h[4 * r + 1], a);
                a = fdot2f16(p2, w2h[4 * r + 2], a);
                acc[r] = fdot2f16(p3, w2h[4 * r + 3], a);
            }
            float t = ((acc[0] + acc[1]) + (acc[2] + acc[3])) +
                      ((acc[4] + acc[5]) + (acc[6] + acc[7]));
            // w3*h2 = w3 - 2*w3/(exp2(t*C+cb2)+1) = fmaf(w3m2, rcp, w3)
            float contrib = fmaf(w3m2, __builtin_amdgcn_rcpf(
                               __builtin_amdgcn_exp2f(fmaf(TWO_LOG2E, t, cb2)) + 1.f), w3);
            __builtin_amdgcn_wave_barrier();       // keep next h1h write after reads
            return wave_allsum(contrib);           // uniform in all lanes
        };

        const float DT   = (float)HOR / (float)(HOR - 1);   // 10/9
        const float DT3  = DT * (1.f / 3.f);
        const float DT8  = DT * 0.125f;
        const float dte  = DT  * ew1;     // per-lane step constants in exponent space
        const float dte3 = DT3 * ew1;
        const float dte8 = DT8 * ew1;

        float base = fmaf(mu, ew1, eb1);  // earg for stage 1
        float c = 0.f;
        if (lane == 0) cs[0] = 0.f;
        for (int t = 1; t < HOR; ++t) {
            // per-step constants with bb3 folded in (all off the serial path)
            float cbase2 = fmaf(bb3, dte3,        base);
            float cbase3 = fmaf(bb3, dte - dte3,  base);
            float cbase4 = fmaf(bb3, dte,         base);

            float S1 = fevalS(base);
            float S2 = fevalS(fmaf(S1, dte3, cbase2));
            float inner3 = fmaf(-dte3, S1, cbase3);            // overlaps stage-2 eval
            float S3 = fevalS(fmaf(S2, dte, inner3));
            float d12 = S1 - S2;                               // overlaps stage-3 eval
            float S4 = fevalS(fmaf(d12 + S3, dte, cbase4));
            float q  = fmaf(3.f, S2 + S3, fmaf(8.f, bb3, S1)); // overlaps stage-4 eval
            float sT = S4 + q;
            base = fmaf(sT, dte8, base);                       // next stage-1 earg
            c = fmaf(sT, DT8, c);                              // off-path bookkeeping
            if (lane == 0) cs[t] = c;
        }
    }
    __syncthreads();

    // ---- write this block's slice: 64 nodes x 10 = 640 floats = 160 float4 ----
    constexpr int NF4 = (M_NODES / NB) * HOR / 4;   // 160
    if (tid < NF4) {
        int e = tid * 4;
        int n = e / 10;
        int h = e - n * 10;
        float4 v;
        v.x = ys[n] + cs[h]; if (++h == 10) { h = 0; ++n; }
        v.y = ys[n] + cs[h]; if (++h == 10) { h = 0; ++n; }
        v.z = ys[n] + cs[h]; if (++h == 10) { h = 0; ++n; }
        v.w = ys[n] + cs[h];
        ((float4*)(out + nbase * HOR))[tid] = v;
    }
}

extern "C" void kernel_launch(void* const* d_in, const int* in_sizes, int n_in,
                              void* d_out, int out_size, void* d_ws, size_t ws_size,
                              hipStream_t stream) {
    const float* x  = (const float*)d_in[0];
    const float* W1 = (const float*)d_in[1];
    const float* b1 = (const float*)d_in[2];
    const float* W2 = (const float*)d_in[3];
    const float* b2 = (const float*)d_in[4];
    const float* W3 = (const float*)d_in[5];
    const float* b3 = (const float*)d_in[6];
    float* out = (float*)d_out;

    fused_gode_kernel<<<NB, 256, 0, stream>>>(x, W1, b1, W2, b2, W3, b3, out);
}

// Round 10
// 16.200 us; speedup vs baseline: 1.2404x; 1.0481x over previous
//
#include <hip/hip_runtime.h>

typedef _Float16 half2_t __attribute__((ext_vector_type(2)));
typedef _Float16 half8_t __attribute__((ext_vector_type(8)));
typedef int      int2v   __attribute__((ext_vector_type(2)));

constexpr int M_NODES = 4096;
constexpr int T_IN    = 24;
constexpr int HIDN    = 64;
constexpr int HOR     = 10;
constexpr int NB      = 64;    // blocks; each owns 64 output nodes, ODE is redundant

constexpr float TWO_LOG2E = 2.8853900817779268f;   // 2*log2(e)

__device__ __forceinline__ float fdot2f16(half2_t a, half2_t b, float c) {
#if __has_builtin(__builtin_amdgcn_fdot2)
    return __builtin_amdgcn_fdot2(a, b, c, false);
#else
    return fmaf((float)a[0], (float)b[0], fmaf((float)a[1], (float)b[1], c));
#endif
}

template<int CTRL, int ROW_MASK>
__device__ __forceinline__ float dpp_add(float v) {
    int t = __builtin_amdgcn_update_dpp(0, __float_as_int(v), CTRL, ROW_MASK, 0xf, true);
    return v + __int_as_float(t);
}

// 64-lane all-reduce sum, result uniform in ALL lanes (no readlane hazard).
__device__ __forceinline__ float wave_allsum(float v) {
    v = dpp_add<0xB1,  0xf>(v);   // quad_perm(1,0,3,2) : xor1
    v = dpp_add<0x4E,  0xf>(v);   // quad_perm(2,3,0,1) : xor2
    v = dpp_add<0x141, 0xf>(v);   // row_half_mirror    : xor4
    v = dpp_add<0x140, 0xf>(v);   // row_mirror         : xor8
#if __has_builtin(__builtin_amdgcn_permlane16_swap) && __has_builtin(__builtin_amdgcn_permlane32_swap)
    {
        int2v r = __builtin_amdgcn_permlane16_swap(__float_as_int(v), __float_as_int(v), false, false);
        v = __int_as_float(r[0]) + __int_as_float(r[1]);
        int2v q = __builtin_amdgcn_permlane32_swap(__float_as_int(v), __float_as_int(v), false, false);
        v = __int_as_float(q[0]) + __int_as_float(q[1]);
    }
    return v;
#else
    v = dpp_add<0x142, 0xa>(v);   // row_bcast:15 -> rows 1,3
    v = dpp_add<0x143, 0xc>(v);   // row_bcast:31 -> rows 2,3; lane63 = total
    return __int_as_float(__builtin_amdgcn_readlane(__float_as_int(v), 63));
#endif
}

__global__ __launch_bounds__(256, 1) void fused_gode_kernel(
    const float* __restrict__ x,
    const float* __restrict__ W1, const float* __restrict__ b1,
    const float* __restrict__ W2, const float* __restrict__ b2,
    const float* __restrict__ W3, const float* __restrict__ b3,
    float* __restrict__ out)
{
    const int tid  = threadIdx.x;
    const int lane = tid & 63;
    const int wid  = tid >> 6;

    __shared__ float psum[256];
    __shared__ float cs[HOR];
    __shared__ __align__(16) _Float16 h1h[HIDN];
    __shared__ float ys[64 + 1];            // this block's y0 slice

    const int nbase = blockIdx.x * (M_NODES / NB);   // 64 nodes per block

    // wave 0: issue weight loads FIRST (latency hides under the reduction)
    float w2f[HIDN];
    float ew1 = 0.f, eb1 = 0.f, cb2 = 0.f, w3 = 0.f, w3m2 = 0.f, bb3 = 0.f;
    if (wid == 0) {
        #pragma unroll
        for (int i = 0; i < HIDN; ++i) w2f[i] = W2[i * HIDN + lane];  // column `lane`
        ew1  = W1[lane] * TWO_LOG2E;      // exp2(y*ew1+eb1) = exp(2*(y*w1+b1))
        eb1  = b1[lane] * TWO_LOG2E;
        cb2  = b2[lane] * TWO_LOG2E;      // seeds the layer-2 accumulation
        w3   = W3[lane];
        w3m2 = -2.f * w3;
        bb3  = b3[0];
    }
    // wave 1: load this block's y0 slice for the write phase
    if (wid == 1) ys[lane] = x[(nbase + lane) * T_IN + (T_IN - 1)];

    // ---- redundant full reduction (identical FP order in every block) ----
    float s = 0.f;
    #pragma unroll
    for (int k = 0; k < M_NODES / 256; ++k)
        s += x[(tid + 256 * k) * T_IN + (T_IN - 1)];
    psum[tid] = s;
    __syncthreads();

    // ---- wave 0: serial scalar ODE (redundant per block, bitwise identical) ----
    if (wid == 0) {
        float t4 = psum[lane] + psum[lane + 64] + psum[lane + 128] + psum[lane + 192];
        float mu = wave_allsum(t4) * (1.0f / (float)M_NODES);

        // W2 column scaled by 2*log2e and packed f16: layer-2 output is already
        // the exp2 argument -> no dependent fma before the second exp2.
        half2_t w2h[HIDN / 2];
        #pragma unroll
        for (int i = 0; i < HIDN; i += 2)
            w2h[i / 2] = half2_t{(_Float16)(w2f[i] * TWO_LOG2E),
                                 (_Float16)(w2f[i + 1] * TWO_LOG2E)};

        // raw-sum feval: returns S where k = S + bb3 (bb3 folded off-path by caller)
        auto fevalS = [&](float earg) -> float {
            float h1 = fmaf(-2.f, __builtin_amdgcn_rcpf(
                               __builtin_amdgcn_exp2f(earg) + 1.f), 1.f);
            h1h[lane] = (_Float16)h1;              // wave-synchronous LDS broadcast
            __builtin_amdgcn_wave_barrier();
            const half8_t* hv = (const half8_t*)h1h;
            float acc[8];
            #pragma unroll
            for (int r = 0; r < 8; ++r) {
                half8_t u = hv[r];                 // uniform addr -> broadcast
                half2_t p0{u[0], u[1]}, p1{u[2], u[3]}, p2{u[4], u[5]}, p3{u[6], u[7]};
                float a = fdot2f16(p0, w2h[4 * r + 0], r == 0 ? cb2 : 0.f);
                a = fdot2f16(p1, w2h[4 * r + 1], a);
                a = fdot2f16(p2, w2h[4 * r + 2], a);
                acc[r] = fdot2f16(p3, w2h[4 * r + 3], a);
            }
            float t = ((acc[0] + acc[1]) + (acc[2] + acc[3])) +
                      ((acc[4] + acc[5]) + (acc[6] + acc[7]));   // = exp2 argument
            float contrib = fmaf(w3m2, __builtin_amdgcn_rcpf(
                               __builtin_amdgcn_exp2f(t) + 1.f), w3);
            __builtin_amdgcn_wave_barrier();       // keep next h1h write after reads
            return wave_allsum(contrib);           // uniform in all lanes
        };

        const float DT   = (float)HOR / (float)(HOR - 1);   // 10/9
        const float DT3  = DT * (1.f / 3.f);
        const float DT8  = DT * 0.125f;
        const float dte  = DT  * ew1;     // per-lane step constants in exponent space
        const float dte3 = DT3 * ew1;
        const float dte8 = DT8 * ew1;

        float base = fmaf(mu, ew1, eb1);  // earg for stage 1
        float c = 0.f;
        if (lane == 0) cs[0] = 0.f;
        for (int t = 1; t < HOR; ++t) {
            // per-step constants with bb3 folded in (all off the serial path)
            float cbase2 = fmaf(bb3, dte3,        base);
            float cbase3 = fmaf(bb3, dte - dte3,  base);
            float cbase4 = fmaf(bb3, dte,         base);

            float S1 = fevalS(base);
            float S2 = fevalS(fmaf(S1, dte3, cbase2));
            float inner3 = fmaf(-dte3, S1, cbase3);            // overlaps stage-2 eval
            float S3 = fevalS(fmaf(S2, dte, inner3));
            float d12 = S1 - S2;                               // overlaps stage-3 eval
            float S4 = fevalS(fmaf(d12 + S3, dte, cbase4));
            float q  = fmaf(3.f, S2 + S3, fmaf(8.f, bb3, S1)); // overlaps stage-4 eval
            float sT = S4 + q;
            base = fmaf(sT, dte8, base);                       // next stage-1 earg
            c = fmaf(sT, DT8, c);                              // off-path bookkeeping
            if (lane == 0) cs[t] = c;
        }
    }
    __syncthreads();

    // ---- write this block's slice: 64 nodes x 10 = 640 floats = 160 float4 ----
    constexpr int NF4 = (M_NODES / NB) * HOR / 4;   // 160
    if (tid < NF4) {
        int e = tid * 4;
        int n = e / 10;
        int h = e - n * 10;
        float4 v;
        v.x = ys[n] + cs[h]; if (++h == 10) { h = 0; ++n; }
        v.y = ys[n] + cs[h]; if (++h == 10) { h = 0; ++n; }
        v.z = ys[n] + cs[h]; if (++h == 10) { h = 0; ++n; }
        v.w = ys[n] + cs[h];
        ((float4*)(out + nbase * HOR))[tid] = v;
    }
}

extern "C" void kernel_launch(void* const* d_in, const int* in_sizes, int n_in,
                              void* d_out, int out_size, void* d_ws, size_t ws_size,
                              hipStream_t stream) {
    const float* x  = (const float*)d_in[0];
    const float* W1 = (const float*)d_in[1];
    const float* b1 = (const float*)d_in[2];
    const float* W2 = (const float*)d_in[3];
    const float* b2 = (const float*)d_in[4];
    const float* W3 = (const float*)d_in[5];
    const float* b3 = (const float*)d_in[6];
    float* out = (float*)d_out;

    fused_gode_kernel<<<NB, 256, 0, stream>>>(x, W1, b1, W2, b2, W3, b3, out);
}